// Round 14
// baseline (293.506 us; speedup 1.0000x reference)
//
#include <hip/hip_runtime.h>
#include <hip/hip_bf16.h>
#include <math.h>

#define DIM 64
#define HID 128
#define NRANGE 4
#define MAXDEG 64

typedef __attribute__((ext_vector_type(8))) short bf16x8;
typedef __attribute__((ext_vector_type(4))) float f32x4;

__device__ __forceinline__ float bf2f(unsigned short us) {
    return __uint_as_float(((unsigned)us) << 16);
}
__device__ __forceinline__ unsigned short f2bf(float f) {
    unsigned u = __float_as_uint(f);
    unsigned r = u + 0x7FFFu + ((u >> 16) & 1u);   // round-to-nearest-even
    return (unsigned short)(r >> 16);
}

// ---- placement into padded CSR, dst-range partitioned (4 ranges) ------------
// slot = d*MAXDEG + cnt[d]++ . NT store on srcs: try to bypass write-allocate.
__global__ __launch_bounds__(256) void place_kernel(const int* __restrict__ src,
                                                    const int* __restrict__ dst,
                                                    int* __restrict__ cnt,
                                                    int* __restrict__ srcs,
                                                    int nedges, int rsize) {
    int r = blockIdx.x & (NRANGE - 1);
    int lo = r * rsize, hi = lo + rsize;
    int tid = (blockIdx.x >> 2) * 256 + threadIdx.x;
    int stride = (gridDim.x >> 2) * 256;
    for (int e = tid; e < nedges; e += stride) {
        int d = dst[e];
        if (d < lo || d >= hi) continue;
        int slot = atomicAdd(&cnt[d], 1);
        __builtin_nontemporal_store(src[e], &srcs[d * MAXDEG + slot]);
    }
}

// ---- node init: dinv = rsqrt(1+deg); xv = bf16(clip_max_norm(x) * dinv) -----
__global__ __launch_bounds__(256) void node_init(const float* __restrict__ emb,
                                                 const int* __restrict__ cnt,
                                                 float* __restrict__ dinv,
                                                 unsigned short* __restrict__ xv,
                                                 int n_nodes) {
    int lane = threadIdx.x & 63;
    int wid = (blockIdx.x * 256 + threadIdx.x) >> 6;
    if (wid >= n_nodes) return;
    float v = emb[(size_t)wid * DIM + lane];
    float s = v * v;
    #pragma unroll
    for (int off = 32; off; off >>= 1) s += __shfl_xor(s, off);
    float sc = fminf(1.0f, 1.0f / (sqrtf(s) + 1e-7f));
    float dn = rsqrtf((float)(1 + cnt[wid]));   // +1 self loop
    if (lane == 0) dinv[wid] = dn;
    xv[(size_t)wid * DIM + lane] = f2bf(v * sc * dn);
}

// ---- gather1: ax[d] = bf16( dinv[d] * (xv[d] + sum_e xv[src_e]) ) -----------
// one wave per node; 4 lane-quarters, 16 lanes x 8B per edge row, 4 edges in
// flight per quarter. Reduce across quarters via shfl_xor(16,32).
__global__ __launch_bounds__(256) void gather_ax(const int* __restrict__ cnt,
                                                 const int* __restrict__ srcs,
                                                 const float* __restrict__ dinv,
                                                 const uint2* __restrict__ xv2,
                                                 uint2* __restrict__ ax2,
                                                 int n_nodes) {
    int lane = threadIdx.x & 63;
    int node = (blockIdx.x * 256 + threadIdx.x) >> 6;
    if (node >= n_nodes) return;
    int q = lane >> 4;       // 0..3
    int li = lane & 15;      // uint2 index within row (4 bf16 per lane)
    int base = node * MAXDEG;
    int end = base + cnt[node];
    float a0 = 0.f, a1 = 0.f, a2 = 0.f, a3 = 0.f;
    if (q == 0) {   // self term
        uint2 v = xv2[(size_t)node * 16 + li];
        a0 = bf2f((unsigned short)v.x); a1 = bf2f((unsigned short)(v.x >> 16));
        a2 = bf2f((unsigned short)v.y); a3 = bf2f((unsigned short)(v.y >> 16));
    }
    int p = base + q;
    for (; p + 12 < end; p += 16) {   // 4 edges per quarter in flight
        int s0 = srcs[p], s1 = srcs[p + 4], s2 = srcs[p + 8], s3 = srcs[p + 12];
        uint2 v0 = xv2[(size_t)s0 * 16 + li];
        uint2 v1 = xv2[(size_t)s1 * 16 + li];
        uint2 v2 = xv2[(size_t)s2 * 16 + li];
        uint2 v3 = xv2[(size_t)s3 * 16 + li];
        a0 += bf2f((unsigned short)v0.x) + bf2f((unsigned short)v1.x)
            + bf2f((unsigned short)v2.x) + bf2f((unsigned short)v3.x);
        a1 += bf2f((unsigned short)(v0.x >> 16)) + bf2f((unsigned short)(v1.x >> 16))
            + bf2f((unsigned short)(v2.x >> 16)) + bf2f((unsigned short)(v3.x >> 16));
        a2 += bf2f((unsigned short)v0.y) + bf2f((unsigned short)v1.y)
            + bf2f((unsigned short)v2.y) + bf2f((unsigned short)v3.y);
        a3 += bf2f((unsigned short)(v0.y >> 16)) + bf2f((unsigned short)(v1.y >> 16))
            + bf2f((unsigned short)(v2.y >> 16)) + bf2f((unsigned short)(v3.y >> 16));
    }
    for (; p < end; p += 4) {
        int s = srcs[p];
        uint2 v = xv2[(size_t)s * 16 + li];
        a0 += bf2f((unsigned short)v.x); a1 += bf2f((unsigned short)(v.x >> 16));
        a2 += bf2f((unsigned short)v.y); a3 += bf2f((unsigned short)(v.y >> 16));
    }
    a0 += __shfl_xor(a0, 16); a0 += __shfl_xor(a0, 32);
    a1 += __shfl_xor(a1, 16); a1 += __shfl_xor(a1, 32);
    a2 += __shfl_xor(a2, 16); a2 += __shfl_xor(a2, 32);
    a3 += __shfl_xor(a3, 16); a3 += __shfl_xor(a3, 32);
    if (q == 0) {
        float dn = dinv[node];
        uint2 o;
        o.x = (unsigned)f2bf(a0 * dn) | ((unsigned)f2bf(a1 * dn) << 16);
        o.y = (unsigned)f2bf(a2 * dn) | ((unsigned)f2bf(a3 * dn) << 16);
        ax2[(size_t)node * 16 + li] = o;
    }
}

// ---- MFMA fused MLP: hvb = bf16( (relu(ax @ W1 + b1) @ W2) * dinv ) ---------
__global__ __launch_bounds__(256) void mfma_mlp(const unsigned short* __restrict__ ax,
                                                const float* __restrict__ W1,
                                                const float* __restrict__ b1,
                                                const float* __restrict__ W2,
                                                const float* __restrict__ dinv,
                                                unsigned short* __restrict__ hvb,
                                                int n_nodes, int ntiles) {
    __shared__ unsigned short w1t[128][72];   // W1T[n][k] = W1[k][n]
    __shared__ unsigned short w2t[64][136];   // W2T[n][k] = W2[k][n]
    __shared__ unsigned short axl[32][72];
    __shared__ unsigned short hL[32][136];
    __shared__ float b1l[128];
    int tid = threadIdx.x;
    for (int idx = tid; idx < DIM * HID; idx += 256) {
        int k = idx >> 7, n = idx & 127;
        w1t[n][k] = f2bf(W1[idx]);
    }
    for (int idx = tid; idx < HID * DIM; idx += 256) {
        int k = idx >> 6, n = idx & 63;
        w2t[n][k] = f2bf(W2[idx]);
    }
    if (tid < 128) b1l[tid] = b1[tid];
    int lane = tid & 63;
    int w = tid >> 6;
    int l15 = lane & 15;
    int lq = lane >> 4;
    __syncthreads();

    for (int t = blockIdx.x; t < ntiles; t += gridDim.x) {
        int row0 = t * 32;
        {
            int r = tid >> 3, c8 = (tid & 7) * 8;
            int n = row0 + r;
            uint4 v = {0u, 0u, 0u, 0u};
            if (n < n_nodes) v = *(const uint4*)&ax[(size_t)n * DIM + c8];
            *(uint4*)&axl[r][c8] = v;
        }
        __syncthreads();
        f32x4 acc00 = {}, acc01 = {}, acc10 = {}, acc11 = {};
        #pragma unroll
        for (int kk = 0; kk < 2; ++kk) {
            int kb = kk * 32 + lq * 8;
            bf16x8 a0 = *(const bf16x8*)&axl[l15][kb];
            bf16x8 a1 = *(const bf16x8*)&axl[16 + l15][kb];
            bf16x8 b0 = *(const bf16x8*)&w1t[w * 32 + l15][kb];
            bf16x8 b1v = *(const bf16x8*)&w1t[w * 32 + 16 + l15][kb];
            acc00 = __builtin_amdgcn_mfma_f32_16x16x32_bf16(a0, b0, acc00, 0, 0, 0);
            acc01 = __builtin_amdgcn_mfma_f32_16x16x32_bf16(a0, b1v, acc01, 0, 0, 0);
            acc10 = __builtin_amdgcn_mfma_f32_16x16x32_bf16(a1, b0, acc10, 0, 0, 0);
            acc11 = __builtin_amdgcn_mfma_f32_16x16x32_bf16(a1, b1v, acc11, 0, 0, 0);
        }
        {
            int c0 = w * 32 + l15, c1 = w * 32 + 16 + l15;
            float bb0 = b1l[c0], bb1 = b1l[c1];
            #pragma unroll
            for (int r = 0; r < 4; ++r) {
                hL[lq * 4 + r][c0]      = f2bf(fmaxf(acc00[r] + bb0, 0.f));
                hL[lq * 4 + r][c1]      = f2bf(fmaxf(acc01[r] + bb1, 0.f));
                hL[16 + lq * 4 + r][c0] = f2bf(fmaxf(acc10[r] + bb0, 0.f));
                hL[16 + lq * 4 + r][c1] = f2bf(fmaxf(acc11[r] + bb1, 0.f));
            }
        }
        __syncthreads();
        f32x4 o0 = {}, o1 = {};
        #pragma unroll
        for (int kk = 0; kk < 4; ++kk) {
            int kb = kk * 32 + lq * 8;
            bf16x8 h0 = *(const bf16x8*)&hL[l15][kb];
            bf16x8 h1 = *(const bf16x8*)&hL[16 + l15][kb];
            bf16x8 bw = *(const bf16x8*)&w2t[w * 16 + l15][kb];
            o0 = __builtin_amdgcn_mfma_f32_16x16x32_bf16(h0, bw, o0, 0, 0, 0);
            o1 = __builtin_amdgcn_mfma_f32_16x16x32_bf16(h1, bw, o1, 0, 0, 0);
        }
        #pragma unroll
        for (int r = 0; r < 4; ++r) {
            int row = row0 + lq * 4 + r;
            if (row < n_nodes)
                hvb[(size_t)row * DIM + w * 16 + l15] = f2bf(o0[r] * dinv[row]);
            int row2 = row + 16;
            if (row2 < n_nodes)
                hvb[(size_t)row2 * DIM + w * 16 + l15] = f2bf(o1[r] * dinv[row2]);
        }
        __syncthreads();
    }
}

// ---- fused layer-2 gather + final, batch-wide only --------------------------
__global__ __launch_bounds__(256) void item_final(const int* __restrict__ cnt,
                                                  const int* __restrict__ srcs,
                                                  const float* __restrict__ dinv,
                                                  const unsigned* __restrict__ hvb2,
                                                  const float* __restrict__ b2,
                                                  const float* __restrict__ user_emb,
                                                  const int* __restrict__ u,
                                                  const int* __restrict__ iid,
                                                  float* __restrict__ out,
                                                  int batch) {
    int lane = threadIdx.x & 63;
    int b = (blockIdx.x * 256 + threadIdx.x) >> 6;
    if (b >= batch) return;
    int h = lane >> 5;       // 0..1
    int li = lane & 31;      // uint index within row (2 bf16 per lane)
    int ii = iid[b], uu = u[b];
    float2 uv = *(const float2*)&user_emb[(size_t)uu * DIM + li * 2];
    float s = uv.x * uv.x + uv.y * uv.y;
    #pragma unroll
    for (int off = 16; off; off >>= 1) s += __shfl_xor(s, off);   // same in both halves
    float sc = fminf(1.0f, 1.0f / (sqrtf(s) + 1e-7f));
    float a0 = 0.f, a1 = 0.f;
    if (h == 0) {   // self term
        unsigned v = hvb2[(size_t)ii * 32 + li];
        a0 = bf2f((unsigned short)v);
        a1 = bf2f((unsigned short)(v >> 16));
    }
    int base = ii * MAXDEG;
    int end = base + cnt[ii];
    int p = base + h;
    for (; p + 2 < end; p += 4) {   // 2 edges per half in flight
        int s0 = srcs[p], s1 = srcs[p + 2];
        unsigned v0 = hvb2[(size_t)s0 * 32 + li];
        unsigned v1 = hvb2[(size_t)s1 * 32 + li];
        a0 += bf2f((unsigned short)v0) + bf2f((unsigned short)v1);
        a1 += bf2f((unsigned short)(v0 >> 16)) + bf2f((unsigned short)(v1 >> 16));
    }
    for (; p < end; p += 2) {
        int s = srcs[p];
        unsigned v = hvb2[(size_t)s * 32 + li];
        a0 += bf2f((unsigned short)v);
        a1 += bf2f((unsigned short)(v >> 16));
    }
    a0 += __shfl_xor(a0, 32);
    a1 += __shfl_xor(a1, 32);
    float2 bb = *(const float2*)&b2[li * 2];
    float dn = dinv[ii];
    float item0 = dn * a0 + bb.x;
    float item1 = dn * a1 + bb.y;
    float dot = (uv.x * item0 + uv.y * item1) * sc;
    #pragma unroll
    for (int off = 16; off; off >>= 1) dot += __shfl_xor(dot, off);
    if (lane == 0) out[b] = 1.0f / (1.0f + expf(-dot));
}

extern "C" void kernel_launch(void* const* d_in, const int* in_sizes, int n_in,
                              void* d_out, int out_size, void* d_ws, size_t ws_size,
                              hipStream_t stream) {
    const float* entity = (const float*)d_in[0];
    const float* user   = (const float*)d_in[1];
    const float* W1     = (const float*)d_in[2];
    const float* b1     = (const float*)d_in[3];
    const float* W2     = (const float*)d_in[4];
    const float* b2     = (const float*)d_in[5];
    const int*   u      = (const int*)d_in[6];
    const int*   iid    = (const int*)d_in[7];
    const int*   eidx   = (const int*)d_in[8];

    int N = in_sizes[0] / DIM;      // 100000
    int B = in_sizes[6];            // 8192
    int E = in_sizes[8] / 2;        // 1600000
    const int* src = eidx;
    const int* dst = eidx + E;
    int ntiles = (N + 31) / 32;     // 3125
    int rsize = (N + NRANGE - 1) / NRANGE;   // 25000

    // workspace layout, 16B-aligned segments (~52 MB)
    char* p = (char*)d_ws;
    auto alloc = [&](size_t bytes) { char* r = p; p += (bytes + 15) & ~(size_t)15; return r; };
    int*   cnt  = (int*)alloc((size_t)N * 4);
    float* dinv = (float*)alloc((size_t)N * 4);
    int*   srcs = (int*)alloc((size_t)N * MAXDEG * 4);        // padded CSR
    unsigned short* xv  = (unsigned short*)alloc((size_t)N * DIM * 2);
    unsigned short* ax  = (unsigned short*)alloc((size_t)N * DIM * 2);
    unsigned short* hvb = (unsigned short*)alloc((size_t)N * DIM * 2);
    float* outF = (float*)d_out;

    hipMemsetAsync(cnt, 0, (size_t)N * 4, stream);
    place_kernel<<<2048, 256, 0, stream>>>(src, dst, cnt, srcs, E, rsize);
    node_init<<<(N * 64 + 255) / 256, 256, 0, stream>>>(entity, cnt, dinv, xv, N);
    gather_ax<<<(N * 64 + 255) / 256, 256, 0, stream>>>(cnt, srcs, dinv,
                                                        (const uint2*)xv, (uint2*)ax, N);
    mfma_mlp<<<768, 256, 0, stream>>>(ax, W1, b1, W2, dinv, hvb, N, ntiles);
    item_final<<<(B * 64 + 255) / 256, 256, 0, stream>>>(cnt, srcs, dinv,
                                                         (const unsigned*)hvb, b2,
                                                         user, u, iid, outF, B);
}